// Round 1
// baseline (791.452 us; speedup 1.0000x reference)
//
#include <hip/hip_runtime.h>

#define N_SAMPLES 8192
#define EMBED 128
#define NBINS 11                 // L = num_bins + 1
#define HROW 24                  // per-row hist stride: 11 pos + 11 neg + 2 pad
#define REP 4                    // LDS histogram replicas (contention relief)
#define REPSTRIDE (64 * HROW + 8) // +8 words shifts each replica's banks

typedef __bf16 bf16x8 __attribute__((ext_vector_type(8)));
typedef float f32x4 __attribute__((ext_vector_type(4)));

__device__ inline unsigned short f2bf(float f) {
  unsigned int u = __float_as_uint(f);
  u += 0x7fffu + ((u >> 16) & 1u);   // round-to-nearest-even
  return (unsigned short)(u >> 16);
}

__global__ __launch_bounds__(256) void convert_kernel(const float* __restrict__ x,
                                                      unsigned short* __restrict__ xb) {
  int gid = blockIdx.x * 256 + threadIdx.x;
  if (gid < (N_SAMPLES * EMBED) / 4) {
    float4 v = reinterpret_cast<const float4*>(x)[gid];
    ushort4 o;
    o.x = f2bf(v.x); o.y = f2bf(v.y); o.z = f2bf(v.z); o.w = f2bf(v.w);
    reinterpret_cast<ushort4*>(xb)[gid] = o;
  }
}

__global__ __launch_bounds__(256) void count_labels_kernel(const int* __restrict__ labels,
                                                           int* __restrict__ ccount) {
  int i = blockIdx.x * 256 + threadIdx.x;
  if (i < N_SAMPLES) atomicAdd(&ccount[labels[i]], 1);
}

// Fused dist2-GEMM + soft-histogram. Block = 256 thr (4 waves), 64 rows/block,
// grid.y splits the 8192 columns into 4 chunks of 2048.
__global__ __launch_bounds__(256) void fastap_main_kernel(
    const unsigned short* __restrict__ xb,   // bf16 bits [8192][128]
    const int* __restrict__ labels,
    float* __restrict__ gH) {                // [8192][HROW] global hist
  __shared__ __align__(16) unsigned short sB[16 * 136]; // 16 cols x 128 k, pad->136
  __shared__ float sH[REP * REPSTRIDE];

  const int tid  = threadIdx.x;
  const int wave = tid >> 6;
  const int lane = tid & 63;
  const int l16  = lane & 15;
  const int quad = lane >> 4;
  const int rep  = lane & 3;

  const int rowBase  = blockIdx.x * 64;
  const int colBegin = blockIdx.y * (N_SAMPLES / 4);
  const int colEnd   = colBegin + (N_SAMPLES / 4);

  for (int idx = tid; idx < REP * REPSTRIDE; idx += 256) sH[idx] = 0.f;

  // A fragments: this wave's 16 rows, all K=128, kept in registers.
  // A layout: lane holds A[m = lane&15][k = quad*8 + j], j=0..7, per 32-K chunk.
  bf16x8 afr[4];
  const int arow = rowBase + wave * 16 + l16;
  #pragma unroll
  for (int kb = 0; kb < 4; ++kb)
    afr[kb] = *reinterpret_cast<const bf16x8*>(&xb[arow * EMBED + kb * 32 + quad * 8]);

  int labi[4];
  #pragma unroll
  for (int r = 0; r < 4; ++r)
    labi[r] = labels[rowBase + wave * 16 + quad * 4 + r];

  __syncthreads();

  for (int ct = colBegin; ct < colEnd; ct += 16) {
    // stage B panel: 16 cols x 128 k of bf16 (B[k][n] = x[n][k])
    {
      const int r    = tid >> 4;
      const int kOff = (tid & 15) * 8;
      *reinterpret_cast<uint4*>(&sB[r * 136 + kOff]) =
          *reinterpret_cast<const uint4*>(&xb[(ct + r) * EMBED + kOff]);
    }
    __syncthreads();

    // B layout: lane holds B[k = quad*8 + j][n = lane&15]
    bf16x8 bfr[4];
    #pragma unroll
    for (int kb = 0; kb < 4; ++kb)
      bfr[kb] = *reinterpret_cast<const bf16x8*>(&sB[l16 * 136 + kb * 32 + quad * 8]);

    f32x4 acc = {0.f, 0.f, 0.f, 0.f};
    #pragma unroll
    for (int kb = 0; kb < 4; ++kb)
      acc = __builtin_amdgcn_mfma_f32_16x16x32_bf16(afr[kb], bfr[kb], acc, 0, 0, 0);

    const int j    = ct + l16;            // C/D: col = lane&15
    const int labj = labels[j];

    #pragma unroll
    for (int r = 0; r < 4; ++r) {         // C/D: row = quad*4 + reg
      const int rowLocal = wave * 16 + quad * 4 + r;
      const int i = rowBase + rowLocal;
      if (i == j) continue;               // diagonal excluded from pos & neg
      const float d  = 2.f - 2.f * acc[r];
      const float t  = d * 2.5f;          // d / Delta, Delta = 0.4
      const float kf = floorf(t);
      const int   k  = (int)kf;
      const float w2 = t - kf;
      const float w1 = 1.f - w2;
      const int sel  = (labi[r] == labj) ? 0 : NBINS;
      float* hrow = &sH[rep * REPSTRIDE + rowLocal * HROW + sel];
      if (k >= 0 && k <= 10)  atomicAdd(hrow + k, w1);
      if (k >= -1 && k <= 9)  atomicAdd(hrow + k + 1, w2);
    }
    __syncthreads();   // sB / sH reuse fence
  }

  // flush block-local histograms (sum replicas) to global
  for (int idx = tid; idx < 64 * 22; idx += 256) {
    const int r = idx / 22;
    const int c = idx % 22;
    float v = 0.f;
    #pragma unroll
    for (int p = 0; p < REP; ++p) v += sH[p * REPSTRIDE + r * HROW + c];
    atomicAdd(&gH[(rowBase + r) * HROW + c], v);
  }
}

__global__ __launch_bounds__(256) void row_ap_kernel(
    const float* __restrict__ gH, const int* __restrict__ labels,
    const int* __restrict__ ccount, float* __restrict__ accum) {
  const int i = blockIdx.x * 256 + threadIdx.x;
  float ap = 0.f, val = 0.f;
  const float* h = &gH[i * HROW];
  float Hp = 0.f, Ht = 0.f;
  #pragma unroll
  for (int l = 0; l < NBINS; ++l) {
    const float hp = h[l];
    const float hn = h[NBINS + l];
    Hp += hp;
    Ht += hp + hn;
    if (Ht > 0.f) ap += hp * Hp / Ht;
  }
  const int np = ccount[labels[i]] - 1;   // N_pos = classCount - 1
  if (np > 0) { ap /= (float)np; val = 1.f; } else { ap = 0.f; }

  __shared__ float sa[256], sv[256];
  sa[threadIdx.x] = ap; sv[threadIdx.x] = val;
  __syncthreads();
  for (int s = 128; s > 0; s >>= 1) {
    if (threadIdx.x < s) {
      sa[threadIdx.x] += sa[threadIdx.x + s];
      sv[threadIdx.x] += sv[threadIdx.x + s];
    }
    __syncthreads();
  }
  if (threadIdx.x == 0) {
    atomicAdd(&accum[0], sa[0]);
    atomicAdd(&accum[1], sv[0]);
  }
}

__global__ void finalize_kernel(const float* __restrict__ accum, float* __restrict__ out) {
  const float c = accum[1];
  out[0] = 1.f - (c > 0.f ? accum[0] / c : 0.f);
}

extern "C" void kernel_launch(void* const* d_in, const int* in_sizes, int n_in,
                              void* d_out, int out_size, void* d_ws, size_t ws_size,
                              hipStream_t stream) {
  const float* x      = (const float*)d_in[0];
  const int*   labels = (const int*)d_in[1];
  // d_in[2] = num_bins (always 10; Delta/L hardcoded)
  float* out = (float*)d_out;

  char* ws = (char*)d_ws;
  const size_t XB_BYTES = (size_t)N_SAMPLES * EMBED * 2;      // 2 MiB bf16
  const size_t GH_BYTES = (size_t)N_SAMPLES * HROW * 4;       // 768 KiB
  unsigned short* xb   = (unsigned short*)ws;
  float* gH            = (float*)(ws + XB_BYTES);
  int*   ccount        = (int*)(ws + XB_BYTES + GH_BYTES);
  float* accum         = (float*)(ws + XB_BYTES + GH_BYTES + 512);

  // zero hist + class counts + accumulators (ws is poisoned each launch)
  hipMemsetAsync(gH, 0, GH_BYTES + 512 + 16, stream);

  convert_kernel<<<(N_SAMPLES * EMBED / 4 + 255) / 256, 256, 0, stream>>>(x, xb);
  count_labels_kernel<<<N_SAMPLES / 256, 256, 0, stream>>>(labels, ccount);
  fastap_main_kernel<<<dim3(N_SAMPLES / 64, 4), 256, 0, stream>>>(xb, labels, gH);
  row_ap_kernel<<<N_SAMPLES / 256, 256, 0, stream>>>(gH, labels, ccount, accum);
  finalize_kernel<<<1, 1, 0, stream>>>(accum, out);
}

// Round 2
// 184.381 us; speedup vs baseline: 4.2925x; 4.2925x over previous
//
#include <hip/hip_runtime.h>

#define N_SAMPLES 8192
#define EMBED 128
#define NBINS 11                 // L = num_bins + 1
#define HROW 24                  // per-row hist stride: 11 pos + 11 neg + 2 pad
#define REP 4                    // LDS histogram replicas (contention relief)
#define REPSTRIDE (64 * HROW + 8) // +8 words shifts each replica's banks
#define COLCHUNK 1024            // grid.y = 8 chunks -> 1024 blocks -> 4 blocks/CU
#define WSCALE 65536.0f          // fixed-point weight scale (2^16)

typedef __bf16 bf16x8 __attribute__((ext_vector_type(8)));
typedef float f32x4 __attribute__((ext_vector_type(4)));

__device__ inline unsigned short f2bf(float f) {
  unsigned int u = __float_as_uint(f);
  u += 0x7fffu + ((u >> 16) & 1u);   // round-to-nearest-even
  return (unsigned short)(u >> 16);
}

__global__ __launch_bounds__(256) void convert_kernel(const float* __restrict__ x,
                                                      unsigned short* __restrict__ xb) {
  int gid = blockIdx.x * 256 + threadIdx.x;
  if (gid < (N_SAMPLES * EMBED) / 4) {
    float4 v = reinterpret_cast<const float4*>(x)[gid];
    ushort4 o;
    o.x = f2bf(v.x); o.y = f2bf(v.y); o.z = f2bf(v.z); o.w = f2bf(v.w);
    reinterpret_cast<ushort4*>(xb)[gid] = o;
  }
}

__global__ __launch_bounds__(256) void count_labels_kernel(const int* __restrict__ labels,
                                                           int* __restrict__ ccount) {
  int i = blockIdx.x * 256 + threadIdx.x;
  if (i < N_SAMPLES) atomicAdd(&ccount[labels[i]], 1);
}

// Fused dist2-GEMM + soft-histogram. Block = 256 thr (4 waves), 64 rows/block,
// grid.y splits the 8192 columns into 8 chunks of 1024.
// Histograms are fixed-point u32 (scale 2^16) so all atomics are native
// ds_add_u32 / global_atomic_add_u32 — never fp CAS loops.
__global__ __launch_bounds__(256) void fastap_main_kernel(
    const unsigned short* __restrict__ xb,   // bf16 bits [8192][128]
    const int* __restrict__ labels,
    unsigned* __restrict__ gH) {             // [8192][HROW] global hist (u32 fixed-point)
  __shared__ __align__(16) unsigned short sB[16 * 136]; // 16 cols x 128 k, pad->136
  __shared__ unsigned sH[REP * REPSTRIDE];

  const int tid  = threadIdx.x;
  const int wave = tid >> 6;
  const int lane = tid & 63;
  const int l16  = lane & 15;
  const int quad = lane >> 4;
  const int rep  = lane & 3;

  const int rowBase  = blockIdx.x * 64;
  const int colBegin = blockIdx.y * COLCHUNK;
  const int colEnd   = colBegin + COLCHUNK;

  for (int idx = tid; idx < REP * REPSTRIDE; idx += 256) sH[idx] = 0u;

  // A fragments: this wave's 16 rows, all K=128, kept in registers.
  // A layout: lane holds A[m = lane&15][k = quad*8 + j], j=0..7, per 32-K chunk.
  bf16x8 afr[4];
  const int arow = rowBase + wave * 16 + l16;
  #pragma unroll
  for (int kb = 0; kb < 4; ++kb)
    afr[kb] = *reinterpret_cast<const bf16x8*>(&xb[arow * EMBED + kb * 32 + quad * 8]);

  int labi[4];
  #pragma unroll
  for (int r = 0; r < 4; ++r)
    labi[r] = labels[rowBase + wave * 16 + quad * 4 + r];

  __syncthreads();

  for (int ct = colBegin; ct < colEnd; ct += 16) {
    // stage B panel: 16 cols x 128 k of bf16 (B[k][n] = x[n][k])
    {
      const int r    = tid >> 4;
      const int kOff = (tid & 15) * 8;
      *reinterpret_cast<uint4*>(&sB[r * 136 + kOff]) =
          *reinterpret_cast<const uint4*>(&xb[(ct + r) * EMBED + kOff]);
    }
    __syncthreads();

    // B layout: lane holds B[k = quad*8 + j][n = lane&15]
    bf16x8 bfr[4];
    #pragma unroll
    for (int kb = 0; kb < 4; ++kb)
      bfr[kb] = *reinterpret_cast<const bf16x8*>(&sB[l16 * 136 + kb * 32 + quad * 8]);

    f32x4 acc = {0.f, 0.f, 0.f, 0.f};
    #pragma unroll
    for (int kb = 0; kb < 4; ++kb)
      acc = __builtin_amdgcn_mfma_f32_16x16x32_bf16(afr[kb], bfr[kb], acc, 0, 0, 0);

    const int j    = ct + l16;            // C/D: col = lane&15
    const int labj = labels[j];

    #pragma unroll
    for (int r = 0; r < 4; ++r) {         // C/D: row = quad*4 + reg
      const int rowLocal = wave * 16 + quad * 4 + r;
      const int i = rowBase + rowLocal;
      if (i == j) continue;               // diagonal excluded from pos & neg
      const float d  = 2.f - 2.f * acc[r];
      const float t  = d * 2.5f;          // d / Delta, Delta = 0.4
      const float kf = floorf(t);
      const int   k  = (int)kf;
      const float w2 = t - kf;
      const unsigned w2q = (unsigned)(w2 * WSCALE + 0.5f);
      const unsigned w1q = 65536u - w2q;
      const int sel  = (labi[r] == labj) ? 0 : NBINS;
      unsigned* hrow = &sH[rep * REPSTRIDE + rowLocal * HROW + sel];
      if (k >= 0 && k <= 10)  atomicAdd(hrow + k, w1q);      // ds_add_u32
      if (k >= -1 && k <= 9)  atomicAdd(hrow + k + 1, w2q);  // ds_add_u32
    }
    __syncthreads();   // sB / sH reuse fence
  }

  // flush block-local histograms (sum replicas) to global (native u32 atomic)
  for (int idx = tid; idx < 64 * 22; idx += 256) {
    const int r = idx / 22;
    const int c = idx % 22;
    unsigned v = 0u;
    #pragma unroll
    for (int p = 0; p < REP; ++p) v += sH[p * REPSTRIDE + r * HROW + c];
    atomicAdd(&gH[(rowBase + r) * HROW + c], v);
  }
}

__global__ __launch_bounds__(256) void row_ap_kernel(
    const unsigned* __restrict__ gH, const int* __restrict__ labels,
    const int* __restrict__ ccount, float* __restrict__ accum) {
  const int i = blockIdx.x * 256 + threadIdx.x;
  float ap = 0.f, val = 0.f;
  const unsigned* h = &gH[i * HROW];
  unsigned Hp = 0u, Ht = 0u;
  #pragma unroll
  for (int l = 0; l < NBINS; ++l) {
    const unsigned hp = h[l];
    const unsigned hn = h[NBINS + l];
    Hp += hp;
    Ht += hp + hn;
    if (Ht > 0u)
      ap += (float)hp * (float)Hp / (float)Ht;   // scale: count * 2^16
  }
  ap *= (1.0f / WSCALE);                          // back to count units
  const int np = ccount[labels[i]] - 1;           // N_pos = classCount - 1
  if (np > 0) { ap /= (float)np; val = 1.f; } else { ap = 0.f; }

  __shared__ float sa[256], sv[256];
  sa[threadIdx.x] = ap; sv[threadIdx.x] = val;
  __syncthreads();
  for (int s = 128; s > 0; s >>= 1) {
    if (threadIdx.x < s) {
      sa[threadIdx.x] += sa[threadIdx.x + s];
      sv[threadIdx.x] += sv[threadIdx.x + s];
    }
    __syncthreads();
  }
  if (threadIdx.x == 0) {
    atomicAdd(&accum[0], sa[0]);
    atomicAdd(&accum[1], sv[0]);
  }
}

__global__ void finalize_kernel(const float* __restrict__ accum, float* __restrict__ out) {
  const float c = accum[1];
  out[0] = 1.f - (c > 0.f ? accum[0] / c : 0.f);
}

extern "C" void kernel_launch(void* const* d_in, const int* in_sizes, int n_in,
                              void* d_out, int out_size, void* d_ws, size_t ws_size,
                              hipStream_t stream) {
  const float* x      = (const float*)d_in[0];
  const int*   labels = (const int*)d_in[1];
  // d_in[2] = num_bins (always 10; Delta/L hardcoded)
  float* out = (float*)d_out;

  char* ws = (char*)d_ws;
  const size_t XB_BYTES = (size_t)N_SAMPLES * EMBED * 2;      // 2 MiB bf16
  const size_t GH_BYTES = (size_t)N_SAMPLES * HROW * 4;       // 768 KiB
  unsigned short* xb   = (unsigned short*)ws;
  unsigned* gH         = (unsigned*)(ws + XB_BYTES);
  int*   ccount        = (int*)(ws + XB_BYTES + GH_BYTES);
  float* accum         = (float*)(ws + XB_BYTES + GH_BYTES + 512);

  // zero hist + class counts + accumulators (ws is poisoned each launch)
  hipMemsetAsync(gH, 0, GH_BYTES + 512 + 16, stream);

  convert_kernel<<<(N_SAMPLES * EMBED / 4 + 255) / 256, 256, 0, stream>>>(x, xb);
  count_labels_kernel<<<N_SAMPLES / 256, 256, 0, stream>>>(labels, ccount);
  fastap_main_kernel<<<dim3(N_SAMPLES / 64, 8), 256, 0, stream>>>(xb, labels, gH);
  row_ap_kernel<<<N_SAMPLES / 256, 256, 0, stream>>>(gH, labels, ccount, accum);
  finalize_kernel<<<1, 1, 0, stream>>>(accum, out);
}